// Round 1
// baseline (484.721 us; speedup 1.0000x reference)
//
#include <hip/hip_runtime.h>
#include <stdint.h>

typedef __attribute__((ext_vector_type(8))) short short8;
typedef __attribute__((ext_vector_type(4))) float floatx4;

__device__ inline unsigned short f2bf(float f){
  union { float fv; unsigned int u; } v; v.fv = f;
  unsigned int u = v.u;
  unsigned int r = ((u >> 16) & 1u) + 0x7FFFu;
  return (unsigned short)((u + r) >> 16);
}

// async global->LDS, 16B per lane, dest = wave-uniform base + lane*16
__device__ __forceinline__ void async16(const void* g, void* l){
  __builtin_amdgcn_global_load_lds(
      (const __attribute__((address_space(1))) unsigned int*)g,
      (__attribute__((address_space(3))) unsigned int*)l, 16, 0, 0);
}

// ---------------- weight prep ----------------
__global__ void prep_w1(const float* __restrict__ w, unsigned short* __restrict__ w1p){
  int i = blockIdx.x*256 + threadIdx.x;
  if (i >= 192*192) return;
  int k = i % 192, o = i / 192;
  int cc = k >> 3, kx = k & 7;
  unsigned short v = 0;
  if (cc < 21 && kx < 7){
    int c = cc / 7, ky = cc % 7;
    v = f2bf(w[(o*3 + c)*49 + ky*7 + kx]);
  }
  w1p[i] = v;
}
__global__ void prep_w2(const float* __restrict__ w, unsigned short* __restrict__ w2p){
  int i = blockIdx.x*256 + threadIdx.x;
  if (i >= 192*9408) return;
  int k = i % 9408, o = i / 9408;
  int g = k / 192, c = k % 192;
  int ky = g / 7, kx = g % 7;
  w2p[i] = f2bf(w[((o*192 + c)*7 + ky)*7 + kx]);
}
__global__ void prep_w3(const float* __restrict__ w, unsigned short* __restrict__ w3p){
  int i = blockIdx.x*256 + threadIdx.x;
  if (i >= 768*8640) return;
  int k = i % 8640, o = i / 8640;
  int g = k / 960, c = k % 960;
  int ky = g / 3, kx = g % 3;
  w3p[i] = f2bf(w[((o*960 + c)*3 + ky)*3 + kx]);
}
__global__ void prep_zp(unsigned int* __restrict__ zp){
  zp[threadIdx.x] = 0u;  // 256 B zero page
}

// ---------------- pad+im2col-kx: x -> xh2[b][c][iy(230)][ox(56)][kx(8)] bf16 ----------------
__global__ void pad_x2(const float* __restrict__ x, unsigned short* __restrict__ xh2){
  int idx = blockIdx.x*256 + threadIdx.x;
  if (idx >= 64*3*230*56*8) return;
  int kx = idx & 7; int t = idx >> 3;
  int ox = t % 56;  t /= 56;
  int iy = t % 230; t /= 230;      // t = b*3 + c
  int row = iy - 3;
  int col = 4*ox - 3 + kx;
  unsigned short v = 0;
  if (row >= 0 && row < 224 && col >= 0 && col < 224)
    v = f2bf(x[((size_t)t*224 + row)*224 + col]);
  xh2[idx] = v;
}

// ---------------- wavelet: per 16x16 block 2D WHT / 16 ----------------
__global__ void wavelet_kernel(const float* __restrict__ x, unsigned short* __restrict__ feat){
  int blk = blockIdx.x;
  int j = blk % 14; blk /= 14;
  int i = blk % 14; blk /= 14;
  int c = blk % 3;  int b = blk / 3;
  int t = threadIdx.x;
  int u = t >> 4, v = t & 15;
  float val = x[((size_t)(b*3 + c)*224 + (i*16 + u))*224 + (j*16 + v)];
  #pragma unroll
  for (int bit = 1; bit < 64; bit <<= 1){
    float p = __shfl_xor(val, bit);
    val = (t & bit) ? (p - val) : (val + p);
  }
  __shared__ float s[256];
  #pragma unroll
  for (int bit = 64; bit < 256; bit <<= 1){
    s[t] = val; __syncthreads();
    float p = s[t ^ bit]; __syncthreads();
    val = (t & bit) ? (p - val) : (val + p);
  }
  s[t] = val; __syncthreads();
  int k = t;
  int d1 = (k>>6)&3, d2 = (k>>4)&3, d3 = (k>>2)&3, d4 = k&3;
  int mr = (d1>>1) | ((d2>>1)<<1) | ((d3>>1)<<2) | ((d4>>1)<<3);
  int mc = (d1&1)  | ((d2&1)<<1)  | ((d3&1)<<2)  | ((d4&1)<<3);
  float outv = s[mr*16 + mc] * 0.0625f;
  feat[((size_t)((b*14 + i)*14 + j))*960 + (k*3 + c)] = f2bf(outv);
}

// ---------------- conv1: dbuf glds MFMA GEMM, BM=128 BN=64 K=192 (3 iters) ----------------
__global__ __launch_bounds__(256) void conv1_gemm(const unsigned short* __restrict__ xh2,
                                                  const unsigned short* __restrict__ w1p,
                                                  const float* __restrict__ b1,
                                                  unsigned short* __restrict__ sp1){
  __shared__ unsigned short As[2][128*64], Bs[2][64*64];
  int m0 = blockIdx.x*128, n0 = blockIdx.y*64;
  int tid = threadIdx.x, wave = tid >> 6, lane = tid & 63;
  int l16 = lane & 15, quad = lane >> 4;
  int wy = wave >> 1, wx = wave & 1;
  int r8 = lane >> 3, kb = (lane & 7) ^ r8;

  int Abase[4];
  #pragma unroll
  for (int j = 0; j < 4; j++){
    int row = wave*32 + j*8 + r8;
    int m = m0 + row;
    int ox = m % 56; int t = m / 56; int oy = t % 56; int b = t / 56;
    Abase[j] = (b*690 + 4*oy)*448 + ox*8;
  }
  const unsigned short* pB0 = w1p + (n0 + wave*16 + r8)*192 + kb*8;
  const unsigned short* pB1 = pB0 + 8*192;

  int sw = l16 & 7;
  int xo0 = ((quad    ) ^ sw)*8;
  int xo1 = ((quad + 4) ^ sw)*8;
  int aoff[4];
  #pragma unroll
  for (int mt = 0; mt < 4; mt++) aoff[mt] = (wy*64 + mt*16 + l16)*64;
  int boff0 = (wx*32 + l16)*64, boff1 = boff0 + 16*64;

  floatx4 acc[4][2];
  #pragma unroll
  for (int mt = 0; mt < 4; mt++)
    #pragma unroll
    for (int nt = 0; nt < 2; nt++) acc[mt][nt] = (floatx4){0.f,0.f,0.f,0.f};

  auto stage = [&](int i, int buf){
    int cc = i*8 + kb;
    int c = (cc*147) >> 10;
    int ky = cc - 7*c;
    int koff = (c*230 + ky)*448;
    #pragma unroll
    for (int j = 0; j < 4; j++)
      async16(xh2 + Abase[j] + koff, (void*)&As[buf][(wave*32 + j*8)*64]);
    async16(pB0 + i*64, (void*)&Bs[buf][(wave*16    )*64]);
    async16(pB1 + i*64, (void*)&Bs[buf][(wave*16 + 8)*64]);
  };

  stage(0, 0);
  __syncthreads();
  #pragma unroll
  for (int i = 0; i < 3; i++){
    int buf = i & 1;
    if (i < 2) stage(i+1, buf ^ 1);
    #pragma unroll
    for (int ks = 0; ks < 2; ks++){
      int xo = ks ? xo1 : xo0;
      short8 b0 = *(const short8*)&Bs[buf][boff0 + xo];
      short8 b1 = *(const short8*)&Bs[buf][boff1 + xo];
      #pragma unroll
      for (int mt = 0; mt < 4; mt++){
        short8 a = *(const short8*)&As[buf][aoff[mt] + xo];
        acc[mt][0] = __builtin_amdgcn_mfma_f32_16x16x32_bf16(a, b0, acc[mt][0], 0, 0, 0);
        acc[mt][1] = __builtin_amdgcn_mfma_f32_16x16x32_bf16(a, b1, acc[mt][1], 0, 0, 0);
      }
    }
    __syncthreads();
  }

  #pragma unroll
  for (int mt = 0; mt < 4; mt++){
    #pragma unroll
    for (int rg = 0; rg < 4; rg++){
      int row = wy*64 + mt*16 + quad*4 + rg;
      size_t ob = (size_t)(m0 + row)*192;
      #pragma unroll
      for (int nt = 0; nt < 2; nt++){
        int nn = n0 + wx*32 + nt*16 + l16;
        sp1[ob + nn] = f2bf(acc[mt][nt][rg] + b1[nn]);
      }
    }
  }
}

// ---------------- conv2/conv3: wave-private K-split implicit GEMM ----------------
// Block tile 64x64, 4 waves. Each wave owns the FULL 64x64 output (4x4 of
// 16x16x32 frags, 64 acc VGPRs) and a PRIVATE quarter of K. Each wave
// double-buffers its own A/B K=32 slabs via global_load_lds (8 glds/step,
// vmcnt(8) counted waits, depth 2) — NO barriers in the main loop. Each
// staged byte is ds_read exactly once (amplification 1 vs 2 before =>
// 32 FLOP per LDS-read-byte). Partials reduced once at the end through the
// (dead) staging LDS: 4 regions of 16 KB alias the wave buffers.
template<int MODE>
__global__ __launch_bounds__(256) void conv_gemm(const unsigned short* __restrict__ Ain,
                                                 const unsigned short* __restrict__ Bt,
                                                 const float* __restrict__ bias,
                                                 const float* __restrict__ pos,
                                                 const unsigned short* __restrict__ zp,
                                                 void* __restrict__ outp){
  constexpr int OH  = (MODE==2) ? 14 : 7;
  constexpr int OW  = OH;
  constexpr int IH  = (MODE==2) ? 56 : 14;
  constexpr int IW  = IH;
  constexpr int Cin = (MODE==2) ? 192 : 960;
  constexpr int KW  = (MODE==2) ? 7 : 3;
  constexpr int S   = (MODE==2) ? 4 : 2;
  constexpr int P   = (MODE==2) ? 3 : 1;
  constexpr int K   = (MODE==2) ? 9408 : 8640;
  constexpr int NSTEP = K/32;            // 294 / 270
  constexpr int MTI = (MODE==2) ? 196 : 49;
  constexpr int GRP = (MODE==2) ? 24 : 96;

  int id = blockIdx.x;
  int g = id / GRP, rem = id % GRP;
  int mtile = g*8 + (rem & 7), ntile = rem >> 3;
  if (mtile >= MTI) return;
  int m0 = mtile*64, n0 = ntile*64;

  // 64 KB: wave w owns bytes [w*16K, w*16K+16K): A bufs 2x4KB then B bufs 2x4KB.
  __shared__ unsigned short smem[32768];

  int tid = threadIdx.x, wave = tid >> 6, lane = tid & 63;
  int l16 = lane & 15, quad = lane >> 4;

  unsigned short* wbase = &smem[wave*8192];

  // this wave's K-step range
  int s0 = (NSTEP*wave) >> 2;
  int s1 = (NSTEP*(wave+1)) >> 2;
  int n = s1 - s0;

  // wave-uniform k-state (Cin % 32 == 0, so a 32-chunk never crosses a tap)
  int k32 = s0*32;
  int c0 = k32 % Cin;
  int gk = k32 / Cin;
  int kx = gk % KW, ky = gk / KW;

  // staging: call j covers rows 16j+ (lane>>2); lane's granule (lane&3) stores
  // source granule (lane&3)^(row&3) — XOR swizzle, read side applies same XOR.
  int rsub = lane >> 2;                  // 0..15
  int soff = ((lane & 3) ^ (rsub & 3)) * 8;

  int Abase[4], iyb[4], ixb[4];
  const unsigned short* pB[4];
  #pragma unroll
  for (int j = 0; j < 4; j++){
    int R = 16*j + rsub;
    int m = m0 + R;
    int ox = m % OW; int t = m / OW; int oy = t % OH; int b = t / OH;
    iyb[j] = S*oy - P; ixb[j] = S*ox - P;
    Abase[j] = ((b*IH + iyb[j])*IW + ixb[j])*Cin;
    pB[j] = Bt + (size_t)(n0 + R)*K + k32 + soff;
  }

  // fragment read offsets: row l16 (+mi*16), granule quad, swizzled by row&3
  int fro = l16*32 + ((quad ^ (l16 & 3)) * 8);

  floatx4 acc[4][4];
  #pragma unroll
  for (int mi = 0; mi < 4; mi++)
    #pragma unroll
    for (int ni = 0; ni < 4; ni++) acc[mi][ni] = (floatx4){0.f,0.f,0.f,0.f};

  auto stage = [&](int buf){
    int koff = (ky*IW + kx)*Cin + c0;
    #pragma unroll
    for (int j = 0; j < 4; j++){
      int iy = iyb[j] + ky, ix = ixb[j] + kx;
      bool v = ((unsigned)iy < (unsigned)IH) & ((unsigned)ix < (unsigned)IW);
      const unsigned short* src = v ? (Ain + Abase[j] + koff + soff) : (zp + soff);
      async16(src, (void*)(wbase + buf*2048 + j*512));
    }
    #pragma unroll
    for (int j = 0; j < 4; j++){
      async16(pB[j], (void*)(wbase + 4096 + buf*2048 + j*512));
      pB[j] += 32;
    }
    c0 += 32;
    if (c0 == Cin){ c0 = 0; kx++; if (kx == KW){ kx = 0; ky++; } }
  };

  auto compute = [&](int buf){
    const unsigned short* Ab = wbase + buf*2048;
    const unsigned short* Bb = wbase + 4096 + buf*2048;
    short8 a[4], b[4];
    #pragma unroll
    for (int i = 0; i < 4; i++){
      a[i] = *(const short8*)&Ab[fro + i*512];
      b[i] = *(const short8*)&Bb[fro + i*512];
    }
    #pragma unroll
    for (int mi = 0; mi < 4; mi++)
      #pragma unroll
      for (int ni = 0; ni < 4; ni++)
        acc[mi][ni] = __builtin_amdgcn_mfma_f32_16x16x32_bf16(a[mi], b[ni], acc[mi][ni], 0, 0, 0);
  };

  // depth-2 wave-private pipeline: 16 glds in flight at each wait point.
  stage(0); stage(1);
  for (int i = 0; i < n-2; i++){
    asm volatile("s_waitcnt vmcnt(8)" ::: "memory");   // buf[i&1] landed
    compute(i & 1);
    asm volatile("s_waitcnt lgkmcnt(0)" ::: "memory"); // reads done before DMA overwrite
    stage(i & 1);
  }
  asm volatile("s_waitcnt vmcnt(8)" ::: "memory");
  compute(n & 1);                       // tile n-2 ((n-2)&1 == n&1)
  asm volatile("s_waitcnt vmcnt(0)" ::: "memory");
  compute((n-1) & 1);

  // ---- reduce 4 K-partials through LDS (regions alias dead staging bufs) ----
  asm volatile("s_waitcnt lgkmcnt(0) vmcnt(0)" ::: "memory");
  __builtin_amdgcn_sched_barrier(0);
  float* red = (float*)wbase;           // own 16 KB region = [64][64] f32
  #pragma unroll
  for (int mi = 0; mi < 4; mi++)
    #pragma unroll
    for (int ni = 0; ni < 4; ni++)
      #pragma unroll
      for (int rg = 0; rg < 4; rg++){
        int row = mi*16 + quad*4 + rg;
        int col = ni*16 + l16;
        red[row*64 + col] = acc[mi][ni][rg];
      }
  __syncthreads();
  const float* r0 = (const float*)&smem[0];
  const float* r1 = (const float*)&smem[8192];
  const float* r2 = (const float*)&smem[16384];
  const float* r3 = (const float*)&smem[24576];
  #pragma unroll
  for (int j = 0; j < 16; j++){
    int e = tid + 256*j;
    float v = r0[e] + r1[e] + r2[e] + r3[e];
    int col = e & 63, row = e >> 6;
    int mm = m0 + row, nn = n0 + col;
    v += bias[nn];
    if (MODE == 2){
      ((unsigned short*)outp)[(size_t)mm*960 + 768 + nn] = f2bf(v);
    } else {
      int b2 = mm / 49;
      int tt = mm - b2*49;
      v += pos[(size_t)(1 + tt)*768 + nn];
      ((float*)outp)[((size_t)(mm + b2 + 1))*768 + nn] = v;
    }
  }
}

// ---------------- cls row ----------------
__global__ void cls_kernel(const float* __restrict__ cls, const float* __restrict__ pos,
                           float* __restrict__ out){
  int i = blockIdx.x*256 + threadIdx.x;
  if (i >= 64*768) return;
  int e = i % 768, b = i / 768;
  out[(size_t)(b*50)*768 + e] = cls[e] + pos[e];
}

extern "C" void kernel_launch(void* const* d_in, const int* in_sizes, int n_in,
                              void* d_out, int out_size, void* d_ws, size_t ws_size,
                              hipStream_t stream){
  (void)in_sizes; (void)n_in; (void)out_size;
  const float* x    = (const float*)d_in[0];
  const float* w_s1 = (const float*)d_in[1];
  const float* b_s1 = (const float*)d_in[2];
  const float* w_s2 = (const float*)d_in[3];
  const float* b_s2 = (const float*)d_in[4];
  const float* w_p  = (const float*)d_in[5];
  const float* b_p  = (const float*)d_in[6];
  const float* cls  = (const float*)d_in[7];
  const float* pos  = (const float*)d_in[8];
  float* out = (float*)d_out;

  char* ws = (char*)d_ws;
  if (ws_size < 118235136u) return;
  unsigned short* w1p  = (unsigned short*)(ws + 0);
  unsigned short* sp1  = (unsigned short*)(ws + 131072);
  unsigned short* zp   = (unsigned short*)(ws + 77201408u);
  unsigned short* w2p  = (unsigned short*)(ws + 77266944u);
  unsigned short* w3p  = (unsigned short*)(ws + 80879616u);
  unsigned short* feat = (unsigned short*)(ws + 94150656u);
  unsigned short* xh2  = (unsigned short*)(ws + 77266944u);

  prep_w1<<<(192*192 + 255)/256, 256, 0, stream>>>(w_s1, w1p);
  pad_x2<<<(64*3*230*56*8)/256, 256, 0, stream>>>(x, xh2);
  conv1_gemm<<<dim3(1568, 3), 256, 0, stream>>>(xh2, w1p, b_s1, sp1);
  prep_w2<<<(192*9408 + 255)/256, 256, 0, stream>>>(w_s2, w2p);
  prep_w3<<<(768*8640 + 255)/256, 256, 0, stream>>>(w_p, w3p);
  prep_zp<<<1, 64, 0, stream>>>((unsigned int*)zp);
  wavelet_kernel<<<64*3*14*14, 256, 0, stream>>>(x, feat);
  conv_gemm<2><<<600, 256, 0, stream>>>(sp1, w2p, b_s2, nullptr, zp, (void*)feat);
  conv_gemm<3><<<672, 256, 0, stream>>>(feat, w3p, b_p, pos, zp, (void*)out);
  cls_kernel<<<(64*768 + 255)/256, 256, 0, stream>>>(cls, pos, out);
}

// Round 3
// 483.242 us; speedup vs baseline: 1.0031x; 1.0031x over previous
//
#include <hip/hip_runtime.h>
#include <stdint.h>

typedef __attribute__((ext_vector_type(8))) short short8;
typedef __attribute__((ext_vector_type(4))) float floatx4;

__device__ inline unsigned short f2bf(float f){
  union { float fv; unsigned int u; } v; v.fv = f;
  unsigned int u = v.u;
  unsigned int r = ((u >> 16) & 1u) + 0x7FFFu;
  return (unsigned short)((u + r) >> 16);
}

// async global->LDS, 16B per lane, dest = wave-uniform base + lane*16
__device__ __forceinline__ void async16(const void* g, void* l){
  __builtin_amdgcn_global_load_lds(
      (const __attribute__((address_space(1))) unsigned int*)g,
      (__attribute__((address_space(3))) unsigned int*)l, 16, 0, 0);
}

// ---------------- weight prep ----------------
__global__ void prep_w1(const float* __restrict__ w, unsigned short* __restrict__ w1p){
  int i = blockIdx.x*256 + threadIdx.x;
  if (i >= 192*192) return;
  int k = i % 192, o = i / 192;
  int cc = k >> 3, kx = k & 7;
  unsigned short v = 0;
  if (cc < 21 && kx < 7){
    int c = cc / 7, ky = cc % 7;
    v = f2bf(w[(o*3 + c)*49 + ky*7 + kx]);
  }
  w1p[i] = v;
}
__global__ void prep_w2(const float* __restrict__ w, unsigned short* __restrict__ w2p){
  int i = blockIdx.x*256 + threadIdx.x;
  if (i >= 192*9408) return;
  int k = i % 9408, o = i / 9408;
  int g = k / 192, c = k % 192;
  int ky = g / 7, kx = g % 7;
  w2p[i] = f2bf(w[((o*192 + c)*7 + ky)*7 + kx]);
}
__global__ void prep_w3(const float* __restrict__ w, unsigned short* __restrict__ w3p){
  int i = blockIdx.x*256 + threadIdx.x;
  if (i >= 768*8640) return;
  int k = i % 8640, o = i / 8640;
  int g = k / 960, c = k % 960;
  int ky = g / 3, kx = g % 3;
  w3p[i] = f2bf(w[((o*960 + c)*3 + ky)*3 + kx]);
}
__global__ void prep_zp(unsigned int* __restrict__ zp){
  zp[threadIdx.x] = 0u;  // 256 B zero page
}

// ---------------- pad+im2col-kx: x -> xh2[b][c][iy(230)][ox(56)][kx(8)] bf16 ----------------
__global__ void pad_x2(const float* __restrict__ x, unsigned short* __restrict__ xh2){
  int idx = blockIdx.x*256 + threadIdx.x;
  if (idx >= 64*3*230*56*8) return;
  int kx = idx & 7; int t = idx >> 3;
  int ox = t % 56;  t /= 56;
  int iy = t % 230; t /= 230;      // t = b*3 + c
  int row = iy - 3;
  int col = 4*ox - 3 + kx;
  unsigned short v = 0;
  if (row >= 0 && row < 224 && col >= 0 && col < 224)
    v = f2bf(x[((size_t)t*224 + row)*224 + col]);
  xh2[idx] = v;
}

// ---------------- wavelet: per 16x16 block 2D WHT / 16 ----------------
__global__ void wavelet_kernel(const float* __restrict__ x, unsigned short* __restrict__ feat){
  int blk = blockIdx.x;
  int j = blk % 14; blk /= 14;
  int i = blk % 14; blk /= 14;
  int c = blk % 3;  int b = blk / 3;
  int t = threadIdx.x;
  int u = t >> 4, v = t & 15;
  float val = x[((size_t)(b*3 + c)*224 + (i*16 + u))*224 + (j*16 + v)];
  #pragma unroll
  for (int bit = 1; bit < 64; bit <<= 1){
    float p = __shfl_xor(val, bit);
    val = (t & bit) ? (p - val) : (val + p);
  }
  __shared__ float s[256];
  #pragma unroll
  for (int bit = 64; bit < 256; bit <<= 1){
    s[t] = val; __syncthreads();
    float p = s[t ^ bit]; __syncthreads();
    val = (t & bit) ? (p - val) : (val + p);
  }
  s[t] = val; __syncthreads();
  int k = t;
  int d1 = (k>>6)&3, d2 = (k>>4)&3, d3 = (k>>2)&3, d4 = k&3;
  int mr = (d1>>1) | ((d2>>1)<<1) | ((d3>>1)<<2) | ((d4>>1)<<3);
  int mc = (d1&1)  | ((d2&1)<<1)  | ((d3&1)<<2)  | ((d4&1)<<3);
  float outv = s[mr*16 + mc] * 0.0625f;
  feat[((size_t)((b*14 + i)*14 + j))*960 + (k*3 + c)] = f2bf(outv);
}

// ---------------- conv1: dbuf glds MFMA GEMM, BM=128 BN=64 K=192 (3 iters) ----------------
__global__ __launch_bounds__(256) void conv1_gemm(const unsigned short* __restrict__ xh2,
                                                  const unsigned short* __restrict__ w1p,
                                                  const float* __restrict__ b1,
                                                  unsigned short* __restrict__ sp1){
  __shared__ unsigned short As[2][128*64], Bs[2][64*64];
  int m0 = blockIdx.x*128, n0 = blockIdx.y*64;
  int tid = threadIdx.x, wave = tid >> 6, lane = tid & 63;
  int l16 = lane & 15, quad = lane >> 4;
  int wy = wave >> 1, wx = wave & 1;
  int r8 = lane >> 3, kb = (lane & 7) ^ r8;

  int Abase[4];
  #pragma unroll
  for (int j = 0; j < 4; j++){
    int row = wave*32 + j*8 + r8;
    int m = m0 + row;
    int ox = m % 56; int t = m / 56; int oy = t % 56; int b = t / 56;
    Abase[j] = (b*690 + 4*oy)*448 + ox*8;
  }
  const unsigned short* pB0 = w1p + (n0 + wave*16 + r8)*192 + kb*8;
  const unsigned short* pB1 = pB0 + 8*192;

  int sw = l16 & 7;
  int xo0 = ((quad    ) ^ sw)*8;
  int xo1 = ((quad + 4) ^ sw)*8;
  int aoff[4];
  #pragma unroll
  for (int mt = 0; mt < 4; mt++) aoff[mt] = (wy*64 + mt*16 + l16)*64;
  int boff0 = (wx*32 + l16)*64, boff1 = boff0 + 16*64;

  floatx4 acc[4][2];
  #pragma unroll
  for (int mt = 0; mt < 4; mt++)
    #pragma unroll
    for (int nt = 0; nt < 2; nt++) acc[mt][nt] = (floatx4){0.f,0.f,0.f,0.f};

  auto stage = [&](int i, int buf){
    int cc = i*8 + kb;
    int c = (cc*147) >> 10;
    int ky = cc - 7*c;
    int koff = (c*230 + ky)*448;
    #pragma unroll
    for (int j = 0; j < 4; j++)
      async16(xh2 + Abase[j] + koff, (void*)&As[buf][(wave*32 + j*8)*64]);
    async16(pB0 + i*64, (void*)&Bs[buf][(wave*16    )*64]);
    async16(pB1 + i*64, (void*)&Bs[buf][(wave*16 + 8)*64]);
  };

  stage(0, 0);
  __syncthreads();
  #pragma unroll
  for (int i = 0; i < 3; i++){
    int buf = i & 1;
    if (i < 2) stage(i+1, buf ^ 1);
    #pragma unroll
    for (int ks = 0; ks < 2; ks++){
      int xo = ks ? xo1 : xo0;
      short8 b0 = *(const short8*)&Bs[buf][boff0 + xo];
      short8 b1 = *(const short8*)&Bs[buf][boff1 + xo];
      #pragma unroll
      for (int mt = 0; mt < 4; mt++){
        short8 a = *(const short8*)&As[buf][aoff[mt] + xo];
        acc[mt][0] = __builtin_amdgcn_mfma_f32_16x16x32_bf16(a, b0, acc[mt][0], 0, 0, 0);
        acc[mt][1] = __builtin_amdgcn_mfma_f32_16x16x32_bf16(a, b1, acc[mt][1], 0, 0, 0);
      }
    }
    __syncthreads();
  }

  #pragma unroll
  for (int mt = 0; mt < 4; mt++){
    #pragma unroll
    for (int rg = 0; rg < 4; rg++){
      int row = wy*64 + mt*16 + quad*4 + rg;
      size_t ob = (size_t)(m0 + row)*192;
      #pragma unroll
      for (int nt = 0; nt < 2; nt++){
        int nn = n0 + wx*32 + nt*16 + l16;
        sp1[ob + nn] = f2bf(acc[mt][nt][rg] + b1[nn]);
      }
    }
  }
}

// ---------------- conv2/conv3: shared K-128 mega-tiles, wave K-split, 64x64 ----------------
// Block tile 64x64, 4 waves. Per K-128 mega-tile: A (64x128, 16 KB) and B
// (64x128, 16 KB) staged cooperatively (8 glds/wave), double-buffered = 64 KB.
// Rows are 256 B, stored with granule swizzle g' = g ^ (row&7) => ds_read_b128
// is 2-way (free). Each wave computes the FULL 64x64 tile over its PRIVATE
// K-32 window (granules 4w..4w+3): every staged byte is ds_read exactly once
// (half of round-0's LDS read traffic) and there is ONE __syncthreads per
// K-128 (half of round-0's barrier rate), with the vmcnt drain hidden behind
// compute since staging is issued first. K padded to 128 via zero page.
// Epilogue: 4 K-partials reduced through the dead staging LDS.
template<int MODE>
__global__ __launch_bounds__(256) void conv_gemm(const unsigned short* __restrict__ Ain,
                                                 const unsigned short* __restrict__ Bt,
                                                 const float* __restrict__ bias,
                                                 const float* __restrict__ pos,
                                                 const unsigned short* __restrict__ zp,
                                                 void* __restrict__ outp){
  constexpr int OH  = (MODE==2) ? 14 : 7;
  constexpr int OW  = OH;
  constexpr int IH  = (MODE==2) ? 56 : 14;
  constexpr int IW  = IH;
  constexpr int Cin = (MODE==2) ? 192 : 960;
  constexpr int KW  = (MODE==2) ? 7 : 3;
  constexpr int S   = (MODE==2) ? 4 : 2;
  constexpr int P   = (MODE==2) ? 3 : 1;
  constexpr int K   = (MODE==2) ? 9408 : 8640;
  constexpr int NMEGA = (K + 127)/128;     // 74 / 68
  constexpr int MTI = (MODE==2) ? 196 : 49;
  constexpr int GRP = (MODE==2) ? 24 : 96;

  int id = blockIdx.x;
  int g = id / GRP, rem = id % GRP;
  int mtile = g*8 + (rem & 7), ntile = rem >> 3;
  if (mtile >= MTI) return;
  int m0 = mtile*64, n0 = ntile*64;

  // shorts: A bufs at 0 / 8192, B bufs at 16384 / 24576 (each 64 rows x 128)
  __shared__ unsigned short smem[32768];

  int tid = threadIdx.x, wv = tid >> 6, lane = tid & 63;
  int l16 = lane & 15, quad = lane >> 4;

  // ---- staging precompute (per lane) ----
  int lr = lane >> 4;                    // row within a 4-row glds call
  int gp = lane & 15;                    // storage granule position
  int ksoff[4], abase[4], iyb[4], ixb[4];
  const unsigned short* bptr[4];
  #pragma unroll
  for (int j = 0; j < 4; j++){
    int r = wv*16 + j*4 + lr;            // row/col index within the 64-tile
    int gsrc = gp ^ (r & 7);             // source granule for this position
    ksoff[j] = gsrc*8;                   // k offset (shorts)
    int m = m0 + r;
    int ox = m % OW; int t = m / OW; int oy = t % OH; int bb = t / OH;
    iyb[j] = S*oy - P; ixb[j] = S*ox - P;
    abase[j] = ((bb*IH + iyb[j])*IW + ixb[j])*Cin;
    bptr[j] = Bt + (size_t)(n0 + r)*K + ksoff[j];
  }

  // ---- fragment read offset: wave wv's K-32 window = granules 4wv..4wv+3 ----
  int fro = l16*128 + ((4*wv + quad) ^ (l16 & 7))*8;

  floatx4 acc[4][4];
  #pragma unroll
  for (int mi = 0; mi < 4; mi++)
    #pragma unroll
    for (int ni = 0; ni < 4; ni++) acc[mi][ni] = (floatx4){0.f,0.f,0.f,0.f};

  auto stage = [&](int buf, int k0){
    unsigned short* Ad = &smem[buf*8192];
    unsigned short* Bd = &smem[16384 + buf*8192];
    #pragma unroll
    for (int j = 0; j < 4; j++){
      int k = k0 + ksoff[j];
      int c = k % Cin;
      int tp = k / Cin;
      int ky = tp / KW, kx = tp - ky*KW;
      int iy = iyb[j] + ky, ix = ixb[j] + kx;
      bool v = ((unsigned)iy < (unsigned)IH) & ((unsigned)ix < (unsigned)IW) & (k < K);
      const unsigned short* src = v ? (Ain + abase[j] + (ky*IW + kx)*Cin + c) : zp;
      async16(src, (void*)&Ad[(wv*16 + j*4)*128]);
    }
    #pragma unroll
    for (int j = 0; j < 4; j++){
      int k = k0 + ksoff[j];
      const unsigned short* src = (k < K) ? (bptr[j] + k0) : zp;
      async16(src, (void*)&Bd[(wv*16 + j*4)*128]);
    }
  };

  auto compute = [&](int buf){
    const unsigned short* Ab = &smem[buf*8192];
    const unsigned short* Bb = &smem[16384 + buf*8192];
    short8 a[4], b[4];
    #pragma unroll
    for (int i = 0; i < 4; i++){
      a[i] = *(const short8*)&Ab[fro + i*2048];
      b[i] = *(const short8*)&Bb[fro + i*2048];
    }
    #pragma unroll
    for (int mi = 0; mi < 4; mi++)
      #pragma unroll
      for (int ni = 0; ni < 4; ni++)
        acc[mi][ni] = __builtin_amdgcn_mfma_f32_16x16x32_bf16(a[mi], b[ni], acc[mi][ni], 0, 0, 0);
  };

  stage(0, 0);
  __syncthreads();
  for (int i = 0; i < NMEGA; i++){
    int buf = i & 1;
    if (i + 1 < NMEGA) stage(buf ^ 1, (i+1)*128);
    compute(buf);
    __syncthreads();   // drains this iter's glds (landed behind compute) + LDS reads
  }

  // ---- reduce 4 K-partials through LDS (staging bufs are dead) ----
  float* red = (float*)&smem[wv * 8192];   // 16 KB region per wave
  #pragma unroll
  for (int mi = 0; mi < 4; mi++)
    #pragma unroll
    for (int ni = 0; ni < 4; ni++)
      #pragma unroll
      for (int rg = 0; rg < 4; rg++){
        int row = mi*16 + quad*4 + rg;
        int col = ni*16 + l16;
        red[row*64 + col] = acc[mi][ni][rg];
      }
  __syncthreads();
  const float* r0 = (const float*)&smem[0];
  const float* r1 = (const float*)&smem[8192];
  const float* r2 = (const float*)&smem[16384];
  const float* r3 = (const float*)&smem[24576];
  #pragma unroll
  for (int j = 0; j < 16; j++){
    int e = tid + 256*j;
    float v = r0[e] + r1[e] + r2[e] + r3[e];
    int col = e & 63, row = e >> 6;
    int mm = m0 + row, nn = n0 + col;
    v += bias[nn];
    if (MODE == 2){
      ((unsigned short*)outp)[(size_t)mm*960 + 768 + nn] = f2bf(v);
    } else {
      int b2 = mm / 49;
      int tt = mm - b2*49;
      v += pos[(size_t)(1 + tt)*768 + nn];
      ((float*)outp)[((size_t)(mm + b2 + 1))*768 + nn] = v;
    }
  }
}

// ---------------- cls row ----------------
__global__ void cls_kernel(const float* __restrict__ cls, const float* __restrict__ pos,
                           float* __restrict__ out){
  int i = blockIdx.x*256 + threadIdx.x;
  if (i >= 64*768) return;
  int e = i % 768, b = i / 768;
  out[(size_t)(b*50)*768 + e] = cls[e] + pos[e];
}

extern "C" void kernel_launch(void* const* d_in, const int* in_sizes, int n_in,
                              void* d_out, int out_size, void* d_ws, size_t ws_size,
                              hipStream_t stream){
  (void)in_sizes; (void)n_in; (void)out_size;
  const float* x    = (const float*)d_in[0];
  const float* w_s1 = (const float*)d_in[1];
  const float* b_s1 = (const float*)d_in[2];
  const float* w_s2 = (const float*)d_in[3];
  const float* b_s2 = (const float*)d_in[4];
  const float* w_p  = (const float*)d_in[5];
  const float* b_p  = (const float*)d_in[6];
  const float* cls  = (const float*)d_in[7];
  const float* pos  = (const float*)d_in[8];
  float* out = (float*)d_out;

  char* ws = (char*)d_ws;
  if (ws_size < 118235136u) return;
  unsigned short* w1p  = (unsigned short*)(ws + 0);
  unsigned short* sp1  = (unsigned short*)(ws + 131072);
  unsigned short* zp   = (unsigned short*)(ws + 77201408u);
  unsigned short* w2p  = (unsigned short*)(ws + 77266944u);
  unsigned short* w3p  = (unsigned short*)(ws + 80879616u);
  unsigned short* feat = (unsigned short*)(ws + 94150656u);
  unsigned short* xh2  = (unsigned short*)(ws + 77266944u);

  prep_w1<<<(192*192 + 255)/256, 256, 0, stream>>>(w_s1, w1p);
  pad_x2<<<(64*3*230*56*8)/256, 256, 0, stream>>>(x, xh2);
  conv1_gemm<<<dim3(1568, 3), 256, 0, stream>>>(xh2, w1p, b_s1, sp1);
  prep_w2<<<(192*9408 + 255)/256, 256, 0, stream>>>(w_s2, w2p);
  prep_w3<<<(768*8640 + 255)/256, 256, 0, stream>>>(w_p, w3p);
  prep_zp<<<1, 64, 0, stream>>>((unsigned int*)zp);
  wavelet_kernel<<<64*3*14*14, 256, 0, stream>>>(x, feat);
  conv_gemm<2><<<600, 256, 0, stream>>>(sp1, w2p, b_s2, nullptr, zp, (void*)feat);
  conv_gemm<3><<<672, 256, 0, stream>>>(feat, w3p, b_p, pos, zp, (void*)out);
  cls_kernel<<<(64*768 + 255)/256, 256, 0, stream>>>(cls, pos, out);
}